// Round 6
// baseline (14088.612 us; speedup 1.0000x reference)
//
#include <hip/hip_runtime.h>
#include <hip/hip_bf16.h>

#define BB 64
#define VV 2048
#define ENCD 128
#define TT 100
#define EMBD 256
#define DECD 512
#define ATTD 256
#define NVOCAB 29

typedef unsigned int u32;
typedef unsigned short u16;

#define AGT __HIP_MEMORY_SCOPE_AGENT

__device__ __forceinline__ float sigf(float x) { return 1.0f / (1.0f + __expf(-x)); }
__device__ __forceinline__ u16 to_bf16(float f) {
    u32 u = __float_as_uint(f);
    u += 0x7fffu + ((u >> 16) & 1u);       // round-to-nearest-even
    return (u16)(u >> 16);
}
// coherent-at-LLC load (sc0 sc1): immune to stale per-XCD L2 (Guideline 16)
__device__ __forceinline__ float aload(const float* p) {
    return __hip_atomic_load(p, __ATOMIC_RELAXED, AGT);
}

// ---------------- one-time init kernels ----------------

// W_decT[DEC][ATT], W_betaT[DEC][ENC], W2T[e][g] = W_ih[g][256+e]
__global__ __launch_bounds__(256) void k_transpose(const float* __restrict__ W_dec,
                                                   const float* __restrict__ W_beta,
                                                   const float* __restrict__ W_ih,
                                                   float* __restrict__ W_decT,
                                                   float* __restrict__ W_betaT,
                                                   float* __restrict__ W2T) {
    int i = blockIdx.x * 256 + threadIdx.x;
    if (i < DECD * ATTD) {
        int l = i / ATTD, a = i % ATTD;
        W_decT[i] = W_dec[a * DECD + l];
    } else if (i < DECD * ATTD + DECD * ENCD) {
        int j = i - DECD * ATTD;
        int l = j / ENCD, e = j % ENCD;
        W_betaT[j] = W_beta[e * DECD + l];
    } else if (i < DECD * ATTD + DECD * ENCD + ENCD * 2048) {
        int j = i - (DECD * ATTD + DECD * ENCD);
        int e = j >> 11, g = j & 2047;
        W2T[j] = W_ih[g * 384 + 256 + e];
    }
}

// enc_attT[b][a][v] = bf16( enc[b][v][:] . W_enc[a][:] + b_enc[a] )  (8 acc/thread)
__global__ __launch_bounds__(256) void k_enc_att(const float* __restrict__ enc,
                                                 const float* __restrict__ W_enc,
                                                 const float* __restrict__ b_enc,
                                                 u16* __restrict__ enc_attT,
                                                 u16* __restrict__ enc_bf) {
    __shared__ float tile[64][ENCD + 1];
    int b = blockIdx.y, v0 = blockIdx.x * 64;
    int t = threadIdx.x;
    const float* src = enc + ((size_t)b * VV + v0) * ENCD;
    u16* dstb = enc_bf + ((size_t)b * VV + v0) * ENCD;
    for (int i = t; i < 64 * ENCD; i += 256) {
        float x = src[i];
        tile[i >> 7][i & 127] = x;
        dstb[i] = to_bf16(x);
    }
    __syncthreads();
    int vl = t & 63;
    int ag = __builtin_amdgcn_readfirstlane(t >> 6);
    for (int ao = 0; ao < 8; ao++) {
        int a0 = ag * 64 + ao * 8;
        float acc[8];
        #pragma unroll
        for (int j = 0; j < 8; j++) acc[j] = b_enc[a0 + j];
        const float* w = W_enc + (size_t)a0 * ENCD;
        for (int k = 0; k < ENCD; k++) {
            float x = tile[vl][k];
            #pragma unroll
            for (int j = 0; j < 8; j++) acc[j] = fmaf(x, w[j * ENCD + k], acc[j]);
        }
        #pragma unroll
        for (int j = 0; j < 8; j++)
            enc_attT[((size_t)b * ATTD + a0 + j) * VV + v0 + vl] = to_bf16(acc[j]);
    }
}

// mean_enc -> h0,c0 -> dec_att0, gate0, xT(emb0 + h0 rows), lengths output
__global__ __launch_bounds__(512) void k_init(const float* __restrict__ enc,
                                              const int* __restrict__ lens,
                                              const int* __restrict__ captions,
                                              const float* __restrict__ emb_W,
                                              const float* __restrict__ W_init_h,
                                              const float* __restrict__ b_init_h,
                                              const float* __restrict__ W_init_c,
                                              const float* __restrict__ b_init_c,
                                              const float* __restrict__ W_decT,
                                              const float* __restrict__ b_dec,
                                              const float* __restrict__ W_betaT,
                                              const float* __restrict__ b_beta,
                                              float* __restrict__ c0,
                                              float* __restrict__ xT,
                                              float* __restrict__ dec_att,
                                              float* __restrict__ gate0,
                                              float* __restrict__ out_len) {
    __shared__ float part[512];
    __shared__ float mean[ENCD];
    __shared__ float h_s[DECD];
    int b = blockIdx.x, t = threadIdx.x;
    int e = t & 127, ch = t >> 7;
    float s = 0.f;
    const float* rowb = enc + (size_t)b * VV * ENCD;
    for (int v = ch * 512; v < ch * 512 + 512; v++) s += rowb[(size_t)v * ENCD + e];
    part[t] = s;
    __syncthreads();
    if (ch == 0) mean[e] = (part[e] + part[128 + e] + part[256 + e] + part[384 + e]) * (1.0f / VV);
    __syncthreads();
    {
        int d = t;
        float hh = b_init_h[d], cc = b_init_c[d];
        for (int k = 0; k < ENCD; k++) {
            hh = fmaf(mean[k], W_init_h[d * ENCD + k], hh);
            cc = fmaf(mean[k], W_init_c[d * ENCD + k], cc);
        }
        c0[b * DECD + d] = cc;
        h_s[d] = hh;
        xT[(384 + d) * BB + b] = hh;
    }
    __syncthreads();
    if (t < ATTD) {
        float s2 = b_dec[t];
        for (int l = 0; l < DECD; l++) s2 = fmaf(h_s[l], W_decT[l * ATTD + t], s2);
        dec_att[b * ATTD + t] = s2;
    } else if (t < ATTD + ENCD) {
        int ee = t - ATTD;
        float s2 = b_beta[ee];
        for (int l = 0; l < DECD; l++) s2 = fmaf(h_s[l], W_betaT[l * ENCD + ee], s2);
        gate0[b * ENCD + ee] = sigf(s2);
    } else {
        int k = t - 384;
        int cap = captions[b * TT + 0];
        xT[k * BB + b] = emb_W[cap * EMBD + k];
        xT[(k + 128) * BB + b] = emb_W[cap * EMBD + k + 128];
    }
    if (t == 0) out_len[b] = (float)lens[b];
}

// ---------------- single per-step kernel (flag-pipelined) ----------------
// blocks 0..255  : scores -> exp -> escoreT(bf16) + dpartT + pawe; release flagS[b]
// blocks 256..639: LSTM gate GEMM kc {0,1,3,4,5,6} (needs only prev xT); release flagG
// blocks 640..767: cell (b,part): spin flagG/flagS[b], gawe+kc2 in-block, cell update,
//                  part0: cout+xT(h)+dec_att+emb; part1: gate_next+preds

struct P {
    const u16* enc_attT; const u16* enc_bf;
    const float* dec_att; const float* w_full; const int* lens; const int* captions;
    const float* emb_W;
    const float* xT_c;  float* xT;
    const float* W_ih; const float* W_hh; const float* b_ih; const float* b_hh;
    const float* W2T; const float* W_final; const float* b_final;
    const float* W_decT; const float* b_dec; const float* W_betaT; const float* b_beta;
    u16* escoreT; float* dpartT; float* pawe; float* gates_part;
    float* gate0; float* gate1; float* c0; float* c1;
    float* dec_att_w; float* preds;
    u32* flagS; u32* flagG;
};

__global__ __launch_bounds__(256) void k_step(P p, int ts) {
    int blk = blockIdx.x, t = threadIdx.x;
    int lane = t & 63, wv = t >> 6;
    if (blk < 256) {
        // -------- score phase --------
        int b = blk >> 2, q = blk & 3, v0 = q << 9;
        if (ts >= p.lens[b]) return;       // no increment; cell(b) also skips
        __shared__ float esh[512];
        __shared__ float dred[4];
        __shared__ float redw[4][ENCD];
        const u32* sp = (const u32*)p.enc_attT + ((size_t)b * ATTD * VV + v0) / 2 + t;
        const float* db = p.dec_att + b * ATTD;   // uniform addr -> s_load
        float s0 = 0.f, s1 = 0.f;
        #pragma unroll 16
        for (int a = 0; a < ATTD; a++) {
            u32 u = sp[(size_t)a * (VV / 2)];
            float da = db[a], wf = p.w_full[a];   // b_full dropped (shift-invariant)
            float x0 = __uint_as_float(u << 16) + da;
            float x1 = __uint_as_float(u & 0xffff0000u) + da;
            s0 = fmaf(fmaxf(x0, 0.f), wf, s0);
            s1 = fmaf(fmaxf(x1, 0.f), wf, s1);
        }
        float e0 = __expf(s0), e1 = __expf(s1);   // |s| < ~3
        ((u32*)p.escoreT)[((size_t)ts * BB * VV + (size_t)b * VV + v0) / 2 + t] =
            (u32)to_bf16(e0) | ((u32)to_bf16(e1) << 16);
        esh[2 * t] = e0;
        esh[2 * t + 1] = e1;
        float ss = e0 + e1;
        for (int o = 32; o > 0; o >>= 1) ss += __shfl_down(ss, o);
        if (lane == 0) dred[wv] = ss;
        __syncthreads();
        if (t == 0) p.dpartT[((size_t)ts * BB + b) * 4 + q] =
                        dred[0] + dred[1] + dred[2] + dred[3];
        const u32* eb = (const u32*)p.enc_bf + ((size_t)b * VV + v0) * ENCD / 2 + lane;
        float a0 = 0.f, a1 = 0.f;
        #pragma unroll 8
        for (int vv = wv; vv < 512; vv += 4) {
            u32 u = eb[(size_t)vv * 64];
            float sc = esh[vv];
            a0 = fmaf(__uint_as_float(u << 16), sc, a0);
            a1 = fmaf(__uint_as_float(u & 0xffff0000u), sc, a1);
        }
        redw[wv][2 * lane] = a0;
        redw[wv][2 * lane + 1] = a1;
        __syncthreads();
        if (t < ENCD)
            p.pawe[((size_t)b * 4 + q) * ENCD + t] =
                redw[0][t] + redw[1][t] + redw[2][t] + redw[3][t];
        __syncthreads();                   // drain all stores (vmcnt0 at barrier)
        if (t == 0) {
            __threadfence();               // L2 writeback to LLC
            __hip_atomic_fetch_add(p.flagS + b, 1u, __ATOMIC_RELEASE, AGT);
        }
    } else if (blk < 640) {
        // -------- attention-independent LSTM GEMM --------
        int idx = blk - 256;
        int kcp = idx >> 6;                // slot 0..5
        int kc = kcp < 2 ? kcp : kcp + 1;  // K chunk {0,1,3,4,5,6}
        int gt = idx & 63;
        int gbase = gt * 32 + wv * 8;
        int gb = __builtin_amdgcn_readfirstlane(gbase);
        int k0 = kc * 128;
        float acc[8];
        #pragma unroll
        for (int j = 0; j < 8; j++)
            acc[j] = (kc == 0) ? (p.b_ih[gb + j] + p.b_hh[gb + j]) : 0.f;
        if (kc < 2) {
            for (int kk = 0; kk < 128; kk++) {
                float xv = p.xT_c[(k0 + kk) * BB + lane];
                #pragma unroll
                for (int j = 0; j < 8; j++)
                    acc[j] = fmaf(xv, p.W_ih[(gb + j) * 384 + k0 + kk], acc[j]);
            }
        } else {
            const float* Wh = p.W_hh + (k0 - 384);
            for (int kk = 0; kk < 128; kk++) {
                float xv = p.xT_c[(k0 + kk) * BB + lane];
                #pragma unroll
                for (int j = 0; j < 8; j++)
                    acc[j] = fmaf(xv, Wh[(gb + j) * DECD + kk], acc[j]);
            }
        }
        float4* o4 = (float4*)(p.gates_part + ((size_t)kcp * BB + lane) * 2048 + gbase);
        o4[0] = make_float4(acc[0], acc[1], acc[2], acc[3]);
        o4[1] = make_float4(acc[4], acc[5], acc[6], acc[7]);
        __syncthreads();
        if (t == 0) {
            __threadfence();
            __hip_atomic_fetch_add(p.flagG, 1u, __ATOMIC_RELEASE, AGT);
        }
    } else {
        // -------- cell phase --------
        int idx = blk - 640;
        int b = idx >> 1, part = idx & 1;
        if (ts >= p.lens[b]) return;
        __shared__ float gawe_s[ENCD];
        __shared__ float h_s[DECD];
        __shared__ float red[256];
        if (t == 0) {
            u32 tgG = 384u * (u32)(ts + 1);
            while (__hip_atomic_load(p.flagG, __ATOMIC_ACQUIRE, AGT) < tgG)
                __builtin_amdgcn_s_sleep(2);
            u32 tgS = 4u * (u32)(ts + 1);
            while (__hip_atomic_load(p.flagS + b, __ATOMIC_ACQUIRE, AGT) < tgS)
                __builtin_amdgcn_s_sleep(2);
        }
        __syncthreads();
        const float* dp = p.dpartT + ((size_t)ts * BB + b) * 4;
        float inv = 1.0f / (aload(dp) + aload(dp + 1) + aload(dp + 2) + aload(dp + 3));
        const float* gprev = (ts & 1) ? p.gate1 : p.gate0;
        float*       gnext = (ts & 1) ? p.gate0 : p.gate1;
        if (t < ENCD) {
            const float* pw = p.pawe + (size_t)b * 4 * ENCD + t;
            float aw = (aload(pw) + aload(pw + ENCD) + aload(pw + 2 * ENCD)
                        + aload(pw + 3 * ENCD)) * inv;
            gawe_s[t] = gprev[b * ENCD + t] * aw;
        }
        __syncthreads();
        const float* cin  = (ts & 1) ? p.c1 : p.c0;
        float*       cout = (ts & 1) ? p.c0 : p.c1;
        // two d per thread: d0 = t, d1 = t+256
        float gi0 = 0.f, gf0 = 0.f, gg0 = 0.f, go0 = 0.f;
        float gi1 = 0.f, gf1 = 0.f, gg1 = 0.f, go1 = 0.f;
        #pragma unroll
        for (int sc = 0; sc < 6; sc++) {
            const float* gp = p.gates_part + ((size_t)sc * BB + b) * 2048;
            gi0 += aload(gp + t);        gi1 += aload(gp + 256 + t);
            gf0 += aload(gp + 512 + t);  gf1 += aload(gp + 768 + t);
            gg0 += aload(gp + 1024 + t); gg1 += aload(gp + 1280 + t);
            go0 += aload(gp + 1536 + t); go1 += aload(gp + 1792 + t);
        }
        #pragma unroll 4
        for (int e = 0; e < ENCD; e++) {   // kc2: W2T rows coalesced, gawe broadcast
            const float* w = p.W2T + (size_t)e * 2048;
            float ge = gawe_s[e];
            gi0 = fmaf(w[t], ge, gi0);        gi1 = fmaf(w[256 + t], ge, gi1);
            gf0 = fmaf(w[512 + t], ge, gf0);  gf1 = fmaf(w[768 + t], ge, gf1);
            gg0 = fmaf(w[1024 + t], ge, gg0); gg1 = fmaf(w[1280 + t], ge, gg1);
            go0 = fmaf(w[1536 + t], ge, go0); go1 = fmaf(w[1792 + t], ge, go1);
        }
        {
            gi0 = sigf(gi0); gf0 = sigf(gf0); go0 = sigf(go0); gg0 = tanhf(gg0);
            float cn = fmaf(gf0, cin[b * DECD + t], gi0 * gg0);
            float hn = go0 * tanhf(cn);
            h_s[t] = hn;
            if (part == 0) { cout[b * DECD + t] = cn; p.xT[(384 + t) * BB + b] = hn; }
        }
        {
            int d = t + 256;
            gi1 = sigf(gi1); gf1 = sigf(gf1); go1 = sigf(go1); gg1 = tanhf(gg1);
            float cn = fmaf(gf1, cin[b * DECD + d], gi1 * gg1);
            float hn = go1 * tanhf(cn);
            h_s[d] = hn;
            if (part == 0) { cout[b * DECD + d] = cn; p.xT[(384 + d) * BB + b] = hn; }
        }
        __syncthreads();
        if (part == 0) {
            float s = p.b_dec[t];                     // dec_att: 256 a, full K=512
            const float* wd = p.W_decT + t;
            #pragma unroll 4
            for (int l = 0; l < DECD; l++) s = fmaf(h_s[l], wd[(size_t)l * ATTD], s);
            p.dec_att_w[b * ATTD + t] = s;
            if (ts + 1 < TT) {                        // emb staging for ts+1
                int cap = p.captions[b * TT + ts + 1];
                p.xT[t * BB + b] = p.emb_W[cap * EMBD + t];
            }
        } else {
            int e = t & 127, half = t >> 7;           // gate: 128 e, K split 2 ways
            float s = 0.f;
            const float* wb = p.W_betaT + (size_t)half * 256 * ENCD + e;
            #pragma unroll 4
            for (int l = 0; l < 256; l++) s = fmaf(h_s[half * 256 + l], wb[(size_t)l * ENCD], s);
            red[t] = s;
            __syncthreads();
            if (t < 128)
                gnext[b * ENCD + t] = sigf(red[t] + red[t + 128] + p.b_beta[t]);
            for (int j = wv; j < NVOCAB; j += 4) {    // predictions
                float s2 = 0.f;
                #pragma unroll
                for (int i = 0; i < 8; i++)
                    s2 = fmaf(h_s[lane + 64 * i], p.W_final[j * DECD + lane + 64 * i], s2);
                for (int o = 32; o > 0; o >>= 1) s2 += __shfl_down(s2, o);
                if (lane == 0) p.preds[((size_t)b * TT + ts) * NVOCAB + j] = s2 + p.b_final[j];
            }
        }
    }
}

// bulk alphas: alphas[b][ts][v] = bf16(escoreT[ts][b][v]) / denom[ts][b]
__global__ __launch_bounds__(256) void k_alphas(const u16* __restrict__ escoreT,
                                                const float* __restrict__ dpartT,
                                                const int* __restrict__ lens,
                                                float* __restrict__ alphas) {
    int ts = blockIdx.x, b = blockIdx.y, t = threadIdx.x;
    if (ts >= lens[b]) return;             // output pre-zeroed
    const float* dp = dpartT + ((size_t)ts * BB + b) * 4;
    float inv = 1.0f / (dp[0] + dp[1] + dp[2] + dp[3]);
    const u32* es = (const u32*)escoreT + ((size_t)ts * BB + b) * VV / 2;
    float2* al = (float2*)(alphas + ((size_t)b * TT + ts) * VV);
    #pragma unroll
    for (int i = t; i < VV / 2; i += 256) {
        u32 u = es[i];
        al[i] = make_float2(__uint_as_float(u << 16) * inv,
                            __uint_as_float(u & 0xffff0000u) * inv);
    }
}

extern "C" void kernel_launch(void* const* d_in, const int* in_sizes, int n_in,
                              void* d_out, int out_size, void* d_ws, size_t ws_size,
                              hipStream_t stream) {
    const float* enc      = (const float*)d_in[0];
    const int*   captions = (const int*)d_in[1];
    const int*   lens     = (const int*)d_in[2];
    const float* emb_W    = (const float*)d_in[3];
    const float* W_enc    = (const float*)d_in[4];
    const float* b_enc    = (const float*)d_in[5];
    const float* W_dec    = (const float*)d_in[6];
    const float* b_dec    = (const float*)d_in[7];
    const float* w_full   = (const float*)d_in[8];
    // d_in[9] b_full: unused — softmax is shift-invariant
    const float* W_ih     = (const float*)d_in[10];
    const float* b_ih     = (const float*)d_in[11];
    const float* W_hh     = (const float*)d_in[12];
    const float* b_hh     = (const float*)d_in[13];
    const float* W_init_h = (const float*)d_in[14];
    const float* b_init_h = (const float*)d_in[15];
    const float* W_init_c = (const float*)d_in[16];
    const float* b_init_c = (const float*)d_in[17];
    const float* W_beta   = (const float*)d_in[18];
    const float* b_beta   = (const float*)d_in[19];
    const float* W_final  = (const float*)d_in[20];
    const float* b_final  = (const float*)d_in[21];

    float* preds   = (float*)d_out;                      // [B][T][VOCAB]
    float* alphas  = preds + (size_t)BB * TT * NVOCAB;   // [B][T][V]
    float* out_len = alphas + (size_t)BB * TT * VV;      // [B] (as float)

    char* ws = (char*)d_ws;
    size_t off = 0;
    auto alloc = [&](size_t bytes) {
        char* p = ws + off;
        off += (bytes + 255) & ~(size_t)255;
        return p;
    };
    u16*   enc_attT   = (u16*)  alloc((size_t)BB * ATTD * VV * sizeof(u16));   // 67 MB
    u16*   enc_bf     = (u16*)  alloc((size_t)BB * VV * ENCD * sizeof(u16));   // 33.5 MB
    u16*   escoreT    = (u16*)  alloc((size_t)TT * BB * VV * sizeof(u16));     // 26.2 MB
    float* dpartT     = (float*)alloc((size_t)TT * BB * 4 * sizeof(float));
    float* pawe       = (float*)alloc((size_t)BB * 4 * ENCD * sizeof(float));
    char*  zbase      = ws + off;                        // zeroed region: flags
    u32*   flagS      = (u32*)  alloc(BB * sizeof(u32));
    u32*   flagG      = (u32*)  alloc(sizeof(u32));
    size_t zbytes     = (size_t)((ws + off) - zbase);
    float* dec_att    = (float*)alloc((size_t)BB * ATTD * sizeof(float));
    float* gate0      = (float*)alloc((size_t)BB * ENCD * sizeof(float));
    float* gate1      = (float*)alloc((size_t)BB * ENCD * sizeof(float));
    float* xT         = (float*)alloc((size_t)896 * BB * sizeof(float));
    float* gates_part = (float*)alloc((size_t)6 * BB * 2048 * sizeof(float));
    float* c0         = (float*)alloc((size_t)BB * DECD * sizeof(float));
    float* c1         = (float*)alloc((size_t)BB * DECD * sizeof(float));
    float* W_decT     = (float*)alloc((size_t)DECD * ATTD * sizeof(float));
    float* W_betaT    = (float*)alloc((size_t)DECD * ENCD * sizeof(float));
    float* W2T        = (float*)alloc((size_t)ENCD * 2048 * sizeof(float));

    hipMemsetAsync(d_out, 0, (size_t)out_size * sizeof(float), stream);
    hipMemsetAsync(zbase, 0, zbytes, stream);            // flags start at 0 each call

    k_transpose<<<1792, 256, 0, stream>>>(W_dec, W_beta, W_ih, W_decT, W_betaT, W2T);
    k_enc_att<<<dim3(VV / 64, BB), 256, 0, stream>>>(enc, W_enc, b_enc, enc_attT, enc_bf);
    k_init<<<BB, 512, 0, stream>>>(enc, lens, captions, emb_W, W_init_h, b_init_h,
                                   W_init_c, b_init_c, W_decT, b_dec, W_betaT, b_beta,
                                   c0, xT, dec_att, gate0, out_len);

    P pv;
    pv.enc_attT = enc_attT; pv.enc_bf = enc_bf;
    pv.dec_att = dec_att; pv.w_full = w_full; pv.lens = lens; pv.captions = captions;
    pv.emb_W = emb_W; pv.xT_c = xT; pv.xT = xT;
    pv.W_ih = W_ih; pv.W_hh = W_hh; pv.b_ih = b_ih; pv.b_hh = b_hh;
    pv.W2T = W2T; pv.W_final = W_final; pv.b_final = b_final;
    pv.W_decT = W_decT; pv.b_dec = b_dec; pv.W_betaT = W_betaT; pv.b_beta = b_beta;
    pv.escoreT = escoreT; pv.dpartT = dpartT; pv.pawe = pawe; pv.gates_part = gates_part;
    pv.gate0 = gate0; pv.gate1 = gate1; pv.c0 = c0; pv.c1 = c1;
    pv.dec_att_w = dec_att; pv.preds = preds;
    pv.flagS = flagS; pv.flagG = flagG;

    for (int t = 0; t < TT; t++)
        k_step<<<768, 256, 0, stream>>>(pv, t);

    k_alphas<<<dim3(TT, BB), 256, 0, stream>>>(escoreT, dpartT, lens, alphas);
}

// Round 7
// 6541.732 us; speedup vs baseline: 2.1537x; 2.1537x over previous
//
#include <hip/hip_runtime.h>
#include <hip/hip_bf16.h>

#define BB 64
#define VV 2048
#define ENCD 128
#define TT 100
#define EMBD 256
#define DECD 512
#define ATTD 256
#define NVOCAB 29

typedef unsigned int u32;
typedef unsigned short u16;
typedef __attribute__((ext_vector_type(2))) float f2;

__device__ __forceinline__ float sigf(float x) { return 1.0f / (1.0f + __expf(-x)); }
__device__ __forceinline__ u16 to_bf16(float f) {
    u32 u = __float_as_uint(f);
    u += 0x7fffu + ((u >> 16) & 1u);       // round-to-nearest-even
    return (u16)(u >> 16);
}

#if __has_builtin(__builtin_amdgcn_cvt_pk_fp8_f32) && __has_builtin(__builtin_amdgcn_cvt_pk_f32_fp8)
#define HAVE_FP8_CVT 1
#endif

// fp8 e4m3fn encode (RNE, subnormals flushed to 0: |err| <= 2^-6 on ~1.5% of values,
// negligible through the 256-term score sum)
__device__ __forceinline__ u32 fp8_enc(float f) {
#ifdef HAVE_FP8_CVT
    return (u32)__builtin_amdgcn_cvt_pk_fp8_f32(f, f, 0, false) & 0xffu;
#else
    u32 u = __float_as_uint(f);
    u32 s = (u >> 24) & 0x80u;
    u32 a = u & 0x7fffffffu;
    u32 r = a + 0x7FFFFu + ((a >> 20) & 1u);
    int v = (int)(r >> 20) - (120 << 3);
    if (v < 8) v = 0;
    if (v > 0x7E) v = 0x7E;
    return s | (u32)v;
#endif
}
__device__ __forceinline__ void fp8x4_dec(u32 u, float* o) {
#ifdef HAVE_FP8_CVT
    f2 lo = __builtin_amdgcn_cvt_pk_f32_fp8((int)u, false);
    f2 hi = __builtin_amdgcn_cvt_pk_f32_fp8((int)u, true);
    o[0] = lo[0]; o[1] = lo[1]; o[2] = hi[0]; o[3] = hi[1];
#else
    #pragma unroll
    for (int i = 0; i < 4; i++) {
        u32 byte = (u >> (8 * i)) & 0xffu;
        u32 s = (byte & 0x80u) << 24;
        u32 m = byte & 0x7fu;
        o[i] = m ? __uint_as_float(s | ((m + (120u << 3)) << 20)) : __uint_as_float(s);
    }
#endif
}

// ---------------- one-time init kernels ----------------

// W_decT[DEC][ATT], W_betaT[DEC][ENC], W2T[e][g] = W_ih[g][256+e]
__global__ __launch_bounds__(256) void k_transpose(const float* __restrict__ W_dec,
                                                   const float* __restrict__ W_beta,
                                                   const float* __restrict__ W_ih,
                                                   float* __restrict__ W_decT,
                                                   float* __restrict__ W_betaT,
                                                   float* __restrict__ W2T) {
    int i = blockIdx.x * 256 + threadIdx.x;
    if (i < DECD * ATTD) {
        int l = i / ATTD, a = i % ATTD;
        W_decT[i] = W_dec[a * DECD + l];
    } else if (i < DECD * ATTD + DECD * ENCD) {
        int j = i - DECD * ATTD;
        int l = j / ENCD, e = j % ENCD;
        W_betaT[j] = W_beta[e * DECD + l];
    } else if (i < DECD * ATTD + DECD * ENCD + ENCD * 2048) {
        int j = i - (DECD * ATTD + DECD * ENCD);
        int e = j >> 11, g = j & 2047;
        W2T[j] = W_ih[g * 384 + 256 + e];
    }
}

// enc_att8[b][q][a][vin] = fp8( enc[b][v][:] . W_enc[a][:] + b_enc[a] ), q = v>>10, vin = v&1023
// layout: per (b,q) score block streams a contiguous 256 KB region. Also emits enc_bf (bf16 enc).
__global__ __launch_bounds__(256) void k_enc_att(const float* __restrict__ enc,
                                                 const float* __restrict__ W_enc,
                                                 const float* __restrict__ b_enc,
                                                 unsigned char* __restrict__ enc_att8,
                                                 u16* __restrict__ enc_bf) {
    __shared__ float tile[64][ENCD + 1];
    int b = blockIdx.y, v0 = blockIdx.x * 64;
    int t = threadIdx.x;
    const float* src = enc + ((size_t)b * VV + v0) * ENCD;
    u16* dstb = enc_bf + ((size_t)b * VV + v0) * ENCD;
    for (int i = t; i < 64 * ENCD; i += 256) {
        float x = src[i];
        tile[i >> 7][i & 127] = x;
        dstb[i] = to_bf16(x);
    }
    __syncthreads();
    int vl = t & 63;
    int ag = __builtin_amdgcn_readfirstlane(t >> 6);   // wave-uniform -> scalar weight loads
    int q = v0 >> 10, vin = (v0 & 1023) + vl;
    unsigned char* dst8 = enc_att8 + (((size_t)(b * 2 + q) * 256) << 10) + vin;
    for (int ao = 0; ao < 8; ao++) {
        int a0 = ag * 64 + ao * 8;
        float acc[8];
        #pragma unroll
        for (int j = 0; j < 8; j++) acc[j] = b_enc[a0 + j];
        const float* w = W_enc + (size_t)a0 * ENCD;
        for (int k = 0; k < ENCD; k++) {
            float x = tile[vl][k];
            #pragma unroll
            for (int j = 0; j < 8; j++) acc[j] = fmaf(x, w[j * ENCD + k], acc[j]);
        }
        #pragma unroll
        for (int j = 0; j < 8; j++)
            dst8[(size_t)(a0 + j) << 10] = (unsigned char)fp8_enc(acc[j]);
    }
}

// mean_enc -> h0,c0 -> dec_att0, gate0, xT(emb0 + h0 rows), lengths output
__global__ __launch_bounds__(512) void k_init(const float* __restrict__ enc,
                                              const int* __restrict__ lens,
                                              const int* __restrict__ captions,
                                              const float* __restrict__ emb_W,
                                              const float* __restrict__ W_init_h,
                                              const float* __restrict__ b_init_h,
                                              const float* __restrict__ W_init_c,
                                              const float* __restrict__ b_init_c,
                                              const float* __restrict__ W_decT,
                                              const float* __restrict__ b_dec,
                                              const float* __restrict__ W_betaT,
                                              const float* __restrict__ b_beta,
                                              float* __restrict__ c0,
                                              float* __restrict__ xT,
                                              float* __restrict__ dec_att,
                                              float* __restrict__ gate0,
                                              float* __restrict__ out_len) {
    __shared__ float part[512];
    __shared__ float mean[ENCD];
    __shared__ float h_s[DECD];
    int b = blockIdx.x, t = threadIdx.x;
    int e = t & 127, ch = t >> 7;
    float s = 0.f;
    const float* rowb = enc + (size_t)b * VV * ENCD;
    for (int v = ch * 512; v < ch * 512 + 512; v++) s += rowb[(size_t)v * ENCD + e];
    part[t] = s;
    __syncthreads();
    if (ch == 0) mean[e] = (part[e] + part[128 + e] + part[256 + e] + part[384 + e]) * (1.0f / VV);
    __syncthreads();
    {
        int d = t;
        float hh = b_init_h[d], cc = b_init_c[d];
        for (int k = 0; k < ENCD; k++) {
            hh = fmaf(mean[k], W_init_h[d * ENCD + k], hh);
            cc = fmaf(mean[k], W_init_c[d * ENCD + k], cc);
        }
        c0[b * DECD + d] = cc;
        h_s[d] = hh;
        xT[(384 + d) * BB + b] = hh;
    }
    __syncthreads();
    if (t < ATTD) {
        float s2 = b_dec[t];
        for (int l = 0; l < DECD; l++) s2 = fmaf(h_s[l], W_decT[l * ATTD + t], s2);
        dec_att[b * ATTD + t] = s2;
    } else if (t < ATTD + ENCD) {
        int ee = t - ATTD;
        float s2 = b_beta[ee];
        for (int l = 0; l < DECD; l++) s2 = fmaf(h_s[l], W_betaT[l * ENCD + ee], s2);
        gate0[b * ENCD + ee] = sigf(s2);
    } else {
        int k = t - 384;
        int cap = captions[b * TT + 0];
        xT[k * BB + b] = emb_W[cap * EMBD + k];
        xT[(k + 128) * BB + b] = emb_W[cap * EMBD + k + 128];
    }
    if (t == 0) out_len[b] = (float)lens[b];
}

// ---------------- per-step kernels (2 per step) ----------------

// blocks 0..127  : scores (fp8, 4 voxels/thread, contiguous layout) -> exp ->
//                  escoreT(bf16) + dpartT[b][q] + pawe[b][q][:]   (no atomics)
// blocks 128..511: LSTM gate partial GEMM kc {0,1,3,4,5,6} (needs only prev-step xT)
__global__ __launch_bounds__(256) void k_att(const unsigned char* __restrict__ enc_att8,
                                             const u16* __restrict__ enc_bf,
                                             const float* __restrict__ dec_att,
                                             const float* __restrict__ w_full,
                                             const int* __restrict__ lens,
                                             const float* __restrict__ xT,
                                             const float* __restrict__ W_ih,
                                             const float* __restrict__ W_hh,
                                             const float* __restrict__ b_ih,
                                             const float* __restrict__ b_hh,
                                             u16* __restrict__ escoreT,
                                             float* __restrict__ dpartT,
                                             float* __restrict__ pawe,
                                             float* __restrict__ gates_part, int ts) {
    int blk = blockIdx.x, t = threadIdx.x;
    int lane = t & 63, wv = t >> 6;
    if (blk < 128) {
        int b = blk >> 1, q = blk & 1;     // 1024 voxels per block, 4 per thread
        if (ts >= lens[b]) return;         // lengths sorted desc; uniform per block
        __shared__ float esh[1024];
        __shared__ float dred[4];
        __shared__ float redw[4][ENCD];
        const u32* sp = (const u32*)enc_att8 + ((size_t)(b * 2 + q) << 16) + t;
        const float* db = dec_att + b * ATTD;   // uniform addr -> s_load
        float s0 = 0.f, s1 = 0.f, s2 = 0.f, s3 = 0.f;
        #pragma unroll 8
        for (int a = 0; a < ATTD; a++) {
            u32 u = sp[(size_t)a * 256];   // contiguous 1KB stride stream
            float x[4];
            fp8x4_dec(u, x);
            float da = db[a], wf = w_full[a];   // b_full dropped (softmax shift-invariant)
            s0 = fmaf(fmaxf(x[0] + da, 0.f), wf, s0);
            s1 = fmaf(fmaxf(x[1] + da, 0.f), wf, s1);
            s2 = fmaf(fmaxf(x[2] + da, 0.f), wf, s2);
            s3 = fmaf(fmaxf(x[3] + da, 0.f), wf, s3);
        }
        float e0 = __expf(s0), e1 = __expf(s1), e2 = __expf(s2), e3 = __expf(s3);
        uint2 pk;
        pk.x = (u32)to_bf16(e0) | ((u32)to_bf16(e1) << 16);
        pk.y = (u32)to_bf16(e2) | ((u32)to_bf16(e3) << 16);
        ((uint2*)escoreT)[(((size_t)ts * BB + b) * VV + (q << 10)) / 4 + t] = pk;
        esh[4 * t] = e0; esh[4 * t + 1] = e1; esh[4 * t + 2] = e2; esh[4 * t + 3] = e3;
        float ss = e0 + e1 + e2 + e3;
        for (int o = 32; o > 0; o >>= 1) ss += __shfl_down(ss, o);
        if (lane == 0) dred[wv] = ss;
        __syncthreads();
        if (t == 0) dpartT[((size_t)ts * BB + b) * 2 + q] =
                        dred[0] + dred[1] + dred[2] + dred[3];
        // awe partial from bf16 encoder, e-pairs packed in u32
        const u32* eb = (const u32*)enc_bf + ((size_t)b * VV + (q << 10)) * (ENCD / 2) + lane;
        float a0 = 0.f, a1 = 0.f;
        #pragma unroll 8
        for (int vv = wv; vv < 1024; vv += 4) {
            u32 u = eb[(size_t)vv * 64];
            float sc = esh[vv];            // wave-uniform -> broadcast
            a0 = fmaf(__uint_as_float(u << 16), sc, a0);
            a1 = fmaf(__uint_as_float(u & 0xffff0000u), sc, a1);
        }
        redw[wv][2 * lane] = a0;
        redw[wv][2 * lane + 1] = a1;
        __syncthreads();
        if (t < ENCD)
            pawe[((size_t)b * 2 + q) * ENCD + t] =
                redw[0][t] + redw[1][t] + redw[2][t] + redw[3][t];
    } else {
        int idx = blk - 128;
        int kcp = idx >> 6;                // slot 0..5
        int kc = kcp < 2 ? kcp : kcp + 1;  // K chunk {0,1,3,4,5,6}
        int gt = idx & 63;
        int gbase = gt * 32 + wv * 8;
        int gb = __builtin_amdgcn_readfirstlane(gbase);   // scalar weight addressing
        int k0 = kc * 128;
        float acc[8];
        #pragma unroll
        for (int j = 0; j < 8; j++)
            acc[j] = (kc == 0) ? (b_ih[gb + j] + b_hh[gb + j]) : 0.f;
        if (kc < 2) {                       // emb columns 0..255
            for (int kk = 0; kk < 128; kk++) {
                float xv = xT[(k0 + kk) * BB + lane];
                #pragma unroll
                for (int j = 0; j < 8; j++)
                    acc[j] = fmaf(xv, W_ih[(gb + j) * 384 + k0 + kk], acc[j]);
            }
        } else {                            // h columns (W_hh cols 0..511)
            const float* Wh = W_hh + (k0 - 384);
            for (int kk = 0; kk < 128; kk++) {
                float xv = xT[(k0 + kk) * BB + lane];
                #pragma unroll
                for (int j = 0; j < 8; j++)
                    acc[j] = fmaf(xv, Wh[(gb + j) * DECD + kk], acc[j]);
            }
        }
        float4* o4 = (float4*)(gates_part + ((size_t)kcp * BB + lane) * 2048 + gbase);
        o4[0] = make_float4(acc[0], acc[1], acc[2], acc[3]);
        o4[1] = make_float4(acc[4], acc[5], acc[6], acc[7]);
    }
}

// 2 parts per b (128 blocks x 512): both sum denom slots -> inv, build gawe, add the
// kc2 contribution in-block (W2T coalesced), cell update. Then:
// part0: cout + xT(h) + dec_att + emb(ts+1); part1: gate_next + preds.
__global__ __launch_bounds__(512) void k_cell(const float* __restrict__ gates_part,
                                              const float* __restrict__ dpartT,
                                              const float* __restrict__ pawe,
                                              const int* __restrict__ lens,
                                              const int* __restrict__ captions,
                                              const float* __restrict__ emb_W,
                                              const float* __restrict__ W2T,
                                              const float* __restrict__ W_final,
                                              const float* __restrict__ b_final,
                                              const float* __restrict__ W_decT,
                                              const float* __restrict__ b_dec,
                                              const float* __restrict__ W_betaT,
                                              const float* __restrict__ b_beta,
                                              float* __restrict__ gate0,
                                              float* __restrict__ gate1,
                                              float* __restrict__ c0,
                                              float* __restrict__ c1,
                                              float* __restrict__ xT,
                                              float* __restrict__ dec_att,
                                              float* __restrict__ preds, int ts) {
    int b = blockIdx.x >> 1, part = blockIdx.x & 1;
    if (ts >= lens[b]) return;             // stale state = correct for masked rows
    __shared__ float gawe_s[ENCD];
    __shared__ float h_s[DECD];
    __shared__ float red[512];
    int t = threadIdx.x;
    const float* dp = dpartT + ((size_t)ts * BB + b) * 2;
    float inv = 1.0f / (dp[0] + dp[1]);
    const float* gprev = (ts & 1) ? gate1 : gate0;   // ping-pong: read-prev/write-next
    float*       gnext = (ts & 1) ? gate0 : gate1;
    if (t < ENCD) {
        const float* pw = pawe + (size_t)b * 2 * ENCD + t;
        float aw = (pw[0] + pw[ENCD]) * inv;
        gawe_s[t] = gprev[b * ENCD + t] * aw;
    }
    __syncthreads();
    const float* cin  = (ts & 1) ? c1 : c0;
    float*       cout = (ts & 1) ? c0 : c1;
    {
        float gi = 0.f, gf = 0.f, gg = 0.f, go = 0.f;
        #pragma unroll
        for (int sc = 0; sc < 6; sc++) {
            const float* gp = gates_part + ((size_t)sc * BB + b) * 2048;
            gi += gp[t]; gf += gp[512 + t]; gg += gp[1024 + t]; go += gp[1536 + t];
        }
        #pragma unroll 4
        for (int e = 0; e < ENCD; e++) {   // kc2: coalesced W2T rows, gawe broadcast
            const float* w = W2T + (size_t)e * 2048;
            float ge = gawe_s[e];
            gi = fmaf(w[t], ge, gi);
            gf = fmaf(w[512 + t], ge, gf);
            gg = fmaf(w[1024 + t], ge, gg);
            go = fmaf(w[1536 + t], ge, go);
        }
        gi = sigf(gi); gf = sigf(gf); go = sigf(go); gg = tanhf(gg);
        float cn = fmaf(gf, cin[b * DECD + t], gi * gg);
        float hn = go * tanhf(cn);
        h_s[t] = hn;
        if (part == 0) {
            cout[b * DECD + t] = cn;
            xT[(384 + t) * BB + b] = hn;
        }
    }
    __syncthreads();
    if (part == 0) {
        int a = t & 255, half = t >> 8;    // dec_att: 256 a, K split 2 ways
        float s = 0.f;
        const float* wd = W_decT + (size_t)half * 256 * ATTD + a;
        #pragma unroll 4
        for (int l = 0; l < 256; l++) s = fmaf(h_s[half * 256 + l], wd[(size_t)l * ATTD], s);
        red[t] = s;
        __syncthreads();
        if (t < 256) {
            dec_att[b * ATTD + t] = red[t] + red[t + 256] + b_dec[t];
        } else if (ts + 1 < TT) {          // emb staging for ts+1 (threads 256..511)
            int k = t - 256;
            int cap = captions[b * TT + ts + 1];
            xT[k * BB + b] = emb_W[cap * EMBD + k];
        }
    } else {
        int e = t & 127, qq = t >> 7;      // gate: 128 e, K split 4 ways
        float s = 0.f;
        const float* wb = W_betaT + (size_t)qq * 128 * ENCD + e;
        #pragma unroll 4
        for (int l = 0; l < 128; l++) s = fmaf(h_s[qq * 128 + l], wb[(size_t)l * ENCD], s);
        red[t] = s;
        __syncthreads();
        if (t < 128)
            gnext[b * ENCD + t] = sigf(red[t] + red[t + 128] + red[t + 256] + red[t + 384]
                                       + b_beta[t]);
        int lane = t & 63, wv = t >> 6;    // predictions: 8 waves over 29 vocab
        for (int j = wv; j < NVOCAB; j += 8) {
            float s2 = 0.f;
            #pragma unroll
            for (int i = 0; i < 8; i++)
                s2 = fmaf(h_s[lane + 64 * i], W_final[j * DECD + lane + 64 * i], s2);
            for (int o = 32; o > 0; o >>= 1) s2 += __shfl_down(s2, o);
            if (lane == 0) preds[((size_t)b * TT + ts) * NVOCAB + j] = s2 + b_final[j];
        }
    }
}

// bulk alphas: alphas[b][ts][v] = bf16(escoreT[ts][b][v]) / denom[ts][b]
__global__ __launch_bounds__(256) void k_alphas(const u16* __restrict__ escoreT,
                                                const float* __restrict__ dpartT,
                                                const int* __restrict__ lens,
                                                float* __restrict__ alphas) {
    int ts = blockIdx.x, b = blockIdx.y, t = threadIdx.x;
    if (ts >= lens[b]) return;             // output pre-zeroed
    const float* dp = dpartT + ((size_t)ts * BB + b) * 2;
    float inv = 1.0f / (dp[0] + dp[1]);
    const u32* es = (const u32*)escoreT + ((size_t)ts * BB + b) * VV / 2;
    float2* al = (float2*)(alphas + ((size_t)b * TT + ts) * VV);
    #pragma unroll
    for (int i = t; i < VV / 2; i += 256) {
        u32 u = es[i];
        al[i] = make_float2(__uint_as_float(u << 16) * inv,
                            __uint_as_float(u & 0xffff0000u) * inv);
    }
}

extern "C" void kernel_launch(void* const* d_in, const int* in_sizes, int n_in,
                              void* d_out, int out_size, void* d_ws, size_t ws_size,
                              hipStream_t stream) {
    const float* enc      = (const float*)d_in[0];
    const int*   captions = (const int*)d_in[1];
    const int*   lens     = (const int*)d_in[2];
    const float* emb_W    = (const float*)d_in[3];
    const float* W_enc    = (const float*)d_in[4];
    const float* b_enc    = (const float*)d_in[5];
    const float* W_dec    = (const float*)d_in[6];
    const float* b_dec    = (const float*)d_in[7];
    const float* w_full   = (const float*)d_in[8];
    // d_in[9] b_full: unused — softmax is shift-invariant
    const float* W_ih     = (const float*)d_in[10];
    const float* b_ih     = (const float*)d_in[11];
    const float* W_hh     = (const float*)d_in[12];
    const float* b_hh     = (const float*)d_in[13];
    const float* W_init_h = (const float*)d_in[14];
    const float* b_init_h = (const float*)d_in[15];
    const float* W_init_c = (const float*)d_in[16];
    const float* b_init_c = (const float*)d_in[17];
    const float* W_beta   = (const float*)d_in[18];
    const float* b_beta   = (const float*)d_in[19];
    const float* W_final  = (const float*)d_in[20];
    const float* b_final  = (const float*)d_in[21];

    float* preds   = (float*)d_out;                      // [B][T][VOCAB]
    float* alphas  = preds + (size_t)BB * TT * NVOCAB;   // [B][T][V]
    float* out_len = alphas + (size_t)BB * TT * VV;      // [B] (as float)

    char* ws = (char*)d_ws;
    size_t off = 0;
    auto alloc = [&](size_t bytes) {
        char* p = ws + off;
        off += (bytes + 255) & ~(size_t)255;
        return p;
    };
    unsigned char* enc_att8 = (unsigned char*)alloc((size_t)BB * ATTD * VV);   // 33.5 MB fp8
    u16*   enc_bf     = (u16*)  alloc((size_t)BB * VV * ENCD * sizeof(u16));   // 33.5 MB
    u16*   escoreT    = (u16*)  alloc((size_t)TT * BB * VV * sizeof(u16));     // 26.2 MB
    float* dpartT     = (float*)alloc((size_t)TT * BB * 2 * sizeof(float));
    float* pawe       = (float*)alloc((size_t)BB * 2 * ENCD * sizeof(float));
    float* dec_att    = (float*)alloc((size_t)BB * ATTD * sizeof(float));
    float* gate0      = (float*)alloc((size_t)BB * ENCD * sizeof(float));
    float* gate1      = (float*)alloc((size_t)BB * ENCD * sizeof(float));
    float* xT         = (float*)alloc((size_t)896 * BB * sizeof(float));
    float* gates_part = (float*)alloc((size_t)6 * BB * 2048 * sizeof(float));
    float* c0         = (float*)alloc((size_t)BB * DECD * sizeof(float));
    float* c1         = (float*)alloc((size_t)BB * DECD * sizeof(float));
    float* W_decT     = (float*)alloc((size_t)DECD * ATTD * sizeof(float));
    float* W_betaT    = (float*)alloc((size_t)DECD * ENCD * sizeof(float));
    float* W2T        = (float*)alloc((size_t)ENCD * 2048 * sizeof(float));

    // masked (b,t) outputs must be exactly 0 (slot buffers need no zero-init:
    // always written by the same step that reads them)
    hipMemsetAsync(d_out, 0, (size_t)out_size * sizeof(float), stream);

    k_transpose<<<1792, 256, 0, stream>>>(W_dec, W_beta, W_ih, W_decT, W_betaT, W2T);
    k_enc_att<<<dim3(VV / 64, BB), 256, 0, stream>>>(enc, W_enc, b_enc, enc_att8, enc_bf);
    k_init<<<BB, 512, 0, stream>>>(enc, lens, captions, emb_W, W_init_h, b_init_h,
                                   W_init_c, b_init_c, W_decT, b_dec, W_betaT, b_beta,
                                   c0, xT, dec_att, gate0, out_len);

    for (int t = 0; t < TT; t++) {
        k_att<<<512, 256, 0, stream>>>(enc_att8, enc_bf, dec_att, w_full, lens, xT,
                                       W_ih, W_hh, b_ih, b_hh, escoreT, dpartT, pawe,
                                       gates_part, t);
        k_cell<<<128, 512, 0, stream>>>(gates_part, dpartT, pawe, lens, captions, emb_W,
                                        W2T, W_final, b_final, W_decT, b_dec, W_betaT,
                                        b_beta, gate0, gate1, c0, c1, xT, dec_att,
                                        preds, t);
    }
    k_alphas<<<dim3(TT, BB), 256, 0, stream>>>(escoreT, dpartT, lens, alphas);
}